// Round 2
// baseline (1208.588 us; speedup 1.0000x reference)
//
#include <hip/hip_runtime.h>
#include <hip/hip_cooperative_groups.h>

namespace cg = cooperative_groups;

// Problem constants: B=8, C=4, H=W=512, K_ITERS=10, ALPHA=2
#define Wd     512
#define W4     128             // float4s per row
#define HWp    262144          // elements per (b,c) plane
#define NTOT   8388608         // B*C*H*W
#define NTILES 1024            // 32 row-chunks x 32 planes

#define F_INF __int_as_float(0x7F800000)

// red[] layout (floats), per-iteration slots (no mid-loop resets):
//   mn[k][plane] = red[k*32 + plane]          (init +INF)
//   mx[k][plane] = red[320 + k*32 + plane]    (init 0; values >= 0)
//   sm[k][plane] = red[640 + k*32 + plane]    (init 0)

__device__ __forceinline__ float4 bound4(const float* __restrict__ pred,
                                         const int* __restrict__ target,
                                         int plane, int v)
{
    const int b = plane >> 2, c = plane & 3;
    float4 p = ((const float4*)(pred + (size_t)plane * HWp))[v];
    int4   t = ((const int4*)(target + (size_t)b * HWp))[v];
    float dx = p.x - (t.x == c ? 1.0f : 0.0f);
    float dy = p.y - (t.y == c ? 1.0f : 0.0f);
    float dz = p.z - (t.z == c ? 1.0f : 0.0f);
    float dw = p.w - (t.w == c ? 1.0f : 0.0f);
    return make_float4(dx*dx, dy*dy, dz*dz, dw*dw);
}

__device__ __forceinline__ float bound1(const float* __restrict__ pred,
                                        const int* __restrict__ target,
                                        int plane, int i)
{
    const int b = plane >> 2, c = plane & 3;
    float p = pred[(size_t)plane * HWp + i];
    int   t = target[(size_t)b * HWp + i];
    float d = p - (t == c ? 1.0f : 0.0f);
    return d * d;
}

// One erosion iteration for one 16-row tile: stencil + wave reduction +
// wave-leader atomics into red[k] slots. Rolling row window: each thread
// owns 8 consecutive rows; only the new bottom row is loaded per step.
// No LDS, no __syncthreads -> safe to call repeatedly (grid-stride).
template <bool FIRST>
__device__ __forceinline__ void iter_body(const float* __restrict__ ip,
                                          float* __restrict__ op,
                                          const float* __restrict__ pred,
                                          const int* __restrict__ target,
                                          float* __restrict__ red,
                                          int k, int plane, int chunk,
                                          float s, float o, bool store)
{
    const float* ipp = FIRST ? (const float*)nullptr : ip + (size_t)plane * HWp;
    float*       opp = op + (size_t)plane * HWp;

    const int tid  = threadIdx.x;
    const int col4 = tid & 127;        // float4 column 0..127
    const int rsub = tid >> 7;         // 0..1
    const int row0 = chunk * 16 + rsub * 8;

    const bool hasL = (col4 > 0);
    const bool hasR = (col4 < W4 - 1);

    auto LD4 = [&](int v) -> float4 {
        if constexpr (FIRST) return bound4(pred, target, plane, v);
        else                 return ((const float4*)ipp)[v];
    };
    auto LD1 = [&](int i) -> float {
        if constexpr (FIRST) return bound1(pred, target, plane, i);
        else                 return ipp[i];
    };

    float lmin = F_INF, lmax = 0.0f, lsum = 0.0f;

    int v = row0 * W4 + col4;                          // center float4 index
    float4 u4 = (row0 > 0) ? LD4(v - W4) : make_float4(0, 0, 0, 0);
    float4 c4 = LD4(v);

    #pragma unroll
    for (int r = 0; r < 8; r++) {
        const int  row  = row0 + r;
        const bool hasU = (row > 0);
        const bool hasD = (row < Wd - 1);
        float4 d4  = hasD ? LD4(v + W4)    : make_float4(0, 0, 0, 0);
        float  lft = hasL ? LD1(4 * v - 1) : 0.0f;
        float  rgt = hasR ? LD1(4 * v + 4) : 0.0f;

        const float vc = (hasU ? 1.0f : 0.0f) + (hasD ? 1.0f : 0.0f);
        float4 sum, cnt;
        sum.x = c4.x + c4.y + u4.x + d4.x + lft;
        cnt.x = 2.0f + (hasL ? 1.0f : 0.0f) + vc;
        sum.y = c4.x + c4.y + c4.z + u4.y + d4.y;
        cnt.y = 3.0f + vc;
        sum.z = c4.y + c4.z + c4.w + u4.z + d4.z;
        cnt.z = 3.0f + vc;
        sum.w = c4.z + c4.w + rgt + u4.w + d4.w;
        cnt.w = 2.0f + (hasR ? 1.0f : 0.0f) + vc;

        float4 e;
        e.x = fmaxf(0.2f * (s * sum.x + o * cnt.x) - 0.5f, 0.0f);
        e.y = fmaxf(0.2f * (s * sum.y + o * cnt.y) - 0.5f, 0.0f);
        e.z = fmaxf(0.2f * (s * sum.z + o * cnt.z) - 0.5f, 0.0f);
        e.w = fmaxf(0.2f * (s * sum.w + o * cnt.w) - 0.5f, 0.0f);

        if (store) ((float4*)opp)[v] = e;

        lmin = fminf(lmin, fminf(fminf(e.x, e.y), fminf(e.z, e.w)));
        lmax = fmaxf(lmax, fmaxf(fmaxf(e.x, e.y), fmaxf(e.z, e.w)));
        lsum += (e.x + e.y) + (e.z + e.w);

        u4 = c4; c4 = d4; v += W4;                      // roll the window
    }

    // wave (64-lane) reduction, then wave-leader atomics (no LDS stage)
    for (int off = 32; off > 0; off >>= 1) {
        lmin = fminf(lmin, __shfl_down(lmin, off));
        lmax = fmaxf(lmax, __shfl_down(lmax, off));
        lsum += __shfl_down(lsum, off);
    }
    if ((tid & 63) == 0) {
        // nonnegative floats: int compare == float compare
        atomicMin((int*)&red[k * 32 + plane],       __float_as_int(lmin));
        atomicMax((int*)&red[320 + k * 32 + plane], __float_as_int(lmax));
        atomicAdd(&red[640 + k * 32 + plane], lsum);
    }
}

__device__ __forceinline__ float final_contrib(const float* __restrict__ red,
                                               int lane)
{
    float contrib = 0.0f;
    if (lane < 32) {
        #pragma unroll
        for (int k = 0; k < 10; k++) {
            float mn = red[k * 32 + lane];
            float mx = red[320 + k * 32 + lane];
            float sm = red[640 + k * 32 + lane];
            float denom = mx - mn;
            float ss = 1.0f, oo = 0.0f;
            if (denom != 0.0f) { ss = 1.0f / denom; oo = -mn / denom; }
            float w = (float)((k + 1) * (k + 1));
            contrib += (ss * sm + oo * 262144.0f) * w;
        }
    }
    for (int off = 16; off > 0; off >>= 1)
        contrib += __shfl_down(contrib, off);
    return contrib;   // valid in lane 0
}

// ---------------- cooperative (preferred) path ----------------
// Grid-stride over NTILES tiles; grid sized by occupancy query on host.
__global__ __launch_bounds__(256, 4) void hausdorff_coop(
    const float* __restrict__ pred, const int* __restrict__ target,
    float* __restrict__ out, float* __restrict__ buf0,
    float* __restrict__ buf1, float* __restrict__ red)
{
    cg::grid_group grid = cg::this_grid();
    const int nblk = gridDim.x;

    for (int tile = blockIdx.x; tile < NTILES; tile += nblk)
        iter_body<true>(nullptr, buf0, pred, target, red, 0,
                        tile >> 5, tile & 31, 1.0f, 0.0f, true);
    grid.sync();

    const float* in = buf0;
    float*       ob = buf1;
    for (int k = 1; k < 10; k++) {
        for (int tile = blockIdx.x; tile < NTILES; tile += nblk) {
            const int plane = tile >> 5, chunk = tile & 31;
            // normalization of iteration k-1 carried as affine (s,o) into k
            float mn = red[(k - 1) * 32 + plane];
            float mx = red[320 + (k - 1) * 32 + plane];
            float denom = mx - mn;
            float ss = 1.0f, oo = 0.0f;
            if (denom != 0.0f) { ss = 1.0f / denom; oo = -mn / denom; }
            iter_body<false>(in, ob, pred, target, red, k, plane, chunk,
                             ss, oo, k < 9);
        }
        grid.sync();
        float* t = (float*)in; in = ob; ob = t;
    }

    if (blockIdx.x == 0 && threadIdx.x < 64) {
        float c = final_contrib(red, threadIdx.x);
        if (threadIdx.x == 0) out[0] = c / 8388608.0f;
    }
}

// ---------------- multi-launch fallback path ----------------
template <bool FIRST>
__global__ __launch_bounds__(256) void stencil_k(const float* __restrict__ in,
                                                 float* __restrict__ out,
                                                 const float* __restrict__ pred,
                                                 const int* __restrict__ target,
                                                 float* __restrict__ red,
                                                 int k, int store)
{
    const int plane = blockIdx.y, chunk = blockIdx.x;
    float s = 1.0f, o = 0.0f;
    if (!FIRST) {
        float mn = red[(k - 1) * 32 + plane];
        float mx = red[320 + (k - 1) * 32 + plane];
        float denom = mx - mn;
        if (denom != 0.0f) { s = 1.0f / denom; o = -mn / denom; }
    }
    iter_body<FIRST>(in, out, pred, target, red, k, plane, chunk, s, o, store != 0);
}

__global__ void final_out(const float* __restrict__ red, float* __restrict__ out)
{
    float c = final_contrib(red, threadIdx.x);
    if (threadIdx.x == 0) out[0] = c / 8388608.0f;
}

extern "C" void kernel_launch(void* const* d_in, const int* in_sizes, int n_in,
                              void* d_out, int out_size, void* d_ws, size_t ws_size,
                              hipStream_t stream)
{
    const float* pred   = (const float*)d_in[0];
    const int*   target = (const int*)d_in[1];
    float* out  = (float*)d_out;
    float* buf0 = (float*)d_ws;
    float* buf1 = buf0 + NTOT;
    float* red  = buf1 + NTOT;

    // init reduction slots: mn -> +INF bit pattern, mx/sm -> 0
    hipMemsetD32Async((hipDeviceptr_t)red, 0x7F800000, 320, stream);
    hipMemsetAsync((void*)(red + 320), 0, 640 * sizeof(float), stream);

    // size the cooperative grid from the runtime's own occupancy query
    // (manual capacity arithmetic refused the launch last time)
    static int coop_blocks = -1;
    if (coop_blocks < 0) {
        int bpc = 0, ncu = 0, dev = 0;
        hipError_t e1 = hipOccupancyMaxActiveBlocksPerMultiprocessor(
            &bpc, (const void*)hausdorff_coop, 256, 0);
        hipGetDevice(&dev);
        hipError_t e2 = hipDeviceGetAttribute(
            &ncu, hipDeviceAttributeMultiprocessorCount, dev);
        coop_blocks = (e1 == hipSuccess && e2 == hipSuccess) ? bpc * ncu : 0;
        if (coop_blocks > NTILES) coop_blocks = NTILES;
    }

    if (coop_blocks >= 64) {
        void* args[] = { &pred, &target, &out, &buf0, &buf1, &red };
        hipError_t e = hipLaunchCooperativeKernel(
            (void*)hausdorff_coop, dim3(coop_blocks), dim3(256), args, 0, stream);
        if (e == hipSuccess) return;
    }

    // fallback: per-k slots let each stencil derive (s,o) itself ->
    // 11 kernel enqueues instead of the baseline's 21
    dim3 grid(32, 32);
    stencil_k<true><<<grid, 256, 0, stream>>>(nullptr, buf0, pred, target, red, 0, 1);
    const float* a = buf0;
    float*       b = buf1;
    for (int k = 1; k < 10; k++) {
        stencil_k<false><<<grid, 256, 0, stream>>>(a, b, pred, target, red, k, (k < 9) ? 1 : 0);
        const float* t = a; a = b; b = (float*)t;
    }
    final_out<<<1, 64, 0, stream>>>(red, out);
}

// Round 3
// 986.625 us; speedup vs baseline: 1.2250x; 1.2250x over previous
//
#include <hip/hip_runtime.h>

// Problem constants: B=8, C=4, H=W=512, K_ITERS=10, ALPHA=2
#define Wd     512
#define W4     128             // float4s per row
#define HWp    262144          // elements per (b,c) plane
#define NTOT   8388608         // B*C*H*W

// red[] layout (960 floats, ALL zero-init; per-iteration slots):
//   cmn[k][plane] = red[k*32 + plane]        unsigned, holds ~bits(min)
//                                            (nonneg floats: ~bits is
//                                             monotone-decreasing, init 0
//                                             never wins an atomicMax)
//   mx [k][plane] = red[320 + k*32 + plane]  float bits via signed atomicMax
//                                            (values >= 0, init 0 ok)
//   sm [k][plane] = red[640 + k*32 + plane]  float atomicAdd

__device__ __forceinline__ float4 bound4(const float* __restrict__ pred,
                                         const int* __restrict__ target,
                                         int plane, int v)
{
    const int b = plane >> 2, c = plane & 3;
    float4 p = ((const float4*)(pred + (size_t)plane * HWp))[v];
    int4   t = ((const int4*)(target + (size_t)b * HWp))[v];
    float dx = p.x - (t.x == c ? 1.0f : 0.0f);
    float dy = p.y - (t.y == c ? 1.0f : 0.0f);
    float dz = p.z - (t.z == c ? 1.0f : 0.0f);
    float dw = p.w - (t.w == c ? 1.0f : 0.0f);
    return make_float4(dx*dx, dy*dy, dz*dz, dw*dw);
}

__device__ __forceinline__ float bound1(const float* __restrict__ pred,
                                        const int* __restrict__ target,
                                        int plane, int i)
{
    const int b = plane >> 2, c = plane & 3;
    float p = pred[(size_t)plane * HWp + i];
    int   t = target[(size_t)b * HWp + i];
    float d = p - (t == c ? 1.0f : 0.0f);
    return d * d;
}

// One erosion pass. Grid: 64 row-chunks (8 rows each) x 32 planes = 2048
// blocks of 256 threads -> 8 blocks/CU, 32 waves/CU (~100% occupancy) to
// hide L2/L3 latency. Each thread owns a 4-row rolling window (1 float4 +
// 2 scalar loads per row). (s,o) of the previous iteration's normalization
// is derived in-kernel from the k-1 reduction slots -> no scalar kernels.
template <bool FIRST>
__global__ __launch_bounds__(256) void stencil_k(const float* __restrict__ in,
                                                 float* __restrict__ out,
                                                 const float* __restrict__ pred,
                                                 const int* __restrict__ target,
                                                 float* __restrict__ red,
                                                 int k, int store)
{
    const int plane = blockIdx.y;
    const int chunk = blockIdx.x;          // 8 rows per chunk

    float s = 1.0f, o = 0.0f;
    if (!FIRST) {
        float mn = __uint_as_float(~((const unsigned*)red)[(k - 1) * 32 + plane]);
        float mx = red[320 + (k - 1) * 32 + plane];
        float denom = mx - mn;
        if (denom != 0.0f) { s = 1.0f / denom; o = -mn / denom; }
    }

    const float* ipp = FIRST ? (const float*)nullptr : in + (size_t)plane * HWp;
    float*       opp = out + (size_t)plane * HWp;

    const int tid  = threadIdx.x;
    const int col4 = tid & 127;            // float4 column 0..127
    const int rsub = tid >> 7;             // 0..1
    const int row0 = chunk * 8 + rsub * 4; // 4-row window

    const bool hasL = (col4 > 0);
    const bool hasR = (col4 < W4 - 1);

    auto LD4 = [&](int v) -> float4 {
        if constexpr (FIRST) return bound4(pred, target, plane, v);
        else                 return ((const float4*)ipp)[v];
    };
    auto LD1 = [&](int i) -> float {
        if constexpr (FIRST) return bound1(pred, target, plane, i);
        else                 return ipp[i];
    };

    float lmin = __int_as_float(0x7F800000), lmax = 0.0f, lsum = 0.0f;

    int v = row0 * W4 + col4;              // center float4 index
    float4 u4 = (row0 > 0) ? LD4(v - W4) : make_float4(0, 0, 0, 0);
    float4 c4 = LD4(v);

    #pragma unroll
    for (int r = 0; r < 4; r++) {
        const int  row  = row0 + r;
        const bool hasU = (row > 0);
        const bool hasD = (row < Wd - 1);
        float4 d4  = hasD ? LD4(v + W4)    : make_float4(0, 0, 0, 0);
        float  lft = hasL ? LD1(4 * v - 1) : 0.0f;
        float  rgt = hasR ? LD1(4 * v + 4) : 0.0f;

        const float vc = (hasU ? 1.0f : 0.0f) + (hasD ? 1.0f : 0.0f);
        float4 sum, cnt;
        sum.x = c4.x + c4.y + u4.x + d4.x + lft;
        cnt.x = 2.0f + (hasL ? 1.0f : 0.0f) + vc;
        sum.y = c4.x + c4.y + c4.z + u4.y + d4.y;
        cnt.y = 3.0f + vc;
        sum.z = c4.y + c4.z + c4.w + u4.z + d4.z;
        cnt.z = 3.0f + vc;
        sum.w = c4.z + c4.w + rgt + u4.w + d4.w;
        cnt.w = 2.0f + (hasR ? 1.0f : 0.0f) + vc;

        float4 e;
        e.x = fmaxf(0.2f * (s * sum.x + o * cnt.x) - 0.5f, 0.0f);
        e.y = fmaxf(0.2f * (s * sum.y + o * cnt.y) - 0.5f, 0.0f);
        e.z = fmaxf(0.2f * (s * sum.z + o * cnt.z) - 0.5f, 0.0f);
        e.w = fmaxf(0.2f * (s * sum.w + o * cnt.w) - 0.5f, 0.0f);

        if (store) ((float4*)opp)[v] = e;

        lmin = fminf(lmin, fminf(fminf(e.x, e.y), fminf(e.z, e.w)));
        lmax = fmaxf(lmax, fmaxf(fmaxf(e.x, e.y), fmaxf(e.z, e.w)));
        lsum += (e.x + e.y) + (e.z + e.w);

        u4 = c4; c4 = d4; v += W4;         // roll the window
    }

    // wave (64-lane) reduction, then wave-leader atomics (no LDS, no sync)
    for (int off = 32; off > 0; off >>= 1) {
        lmin = fminf(lmin, __shfl_down(lmin, off));
        lmax = fmaxf(lmax, __shfl_down(lmax, off));
        lsum += __shfl_down(lsum, off);
    }
    if ((tid & 63) == 0) {
        atomicMax((unsigned*)&red[k * 32 + plane], ~__float_as_uint(lmin));
        atomicMax((int*)&red[320 + k * 32 + plane], __float_as_int(lmax));
        atomicAdd(&red[640 + k * 32 + plane], lsum);
    }
}

// One block, 64 threads: fold all 10x32 plane reductions into the scalar.
__global__ void final_out(const float* __restrict__ red, float* __restrict__ out)
{
    const int lane = threadIdx.x;
    float contrib = 0.0f;
    if (lane < 32) {
        #pragma unroll
        for (int kk = 0; kk < 10; kk++) {
            float mn = __uint_as_float(~((const unsigned*)red)[kk * 32 + lane]);
            float mx = red[320 + kk * 32 + lane];
            float sm = red[640 + kk * 32 + lane];
            float denom = mx - mn;
            float ss = 1.0f, oo = 0.0f;
            if (denom != 0.0f) { ss = 1.0f / denom; oo = -mn / denom; }
            float w = (float)((kk + 1) * (kk + 1));
            contrib += (ss * sm + oo * 262144.0f) * w;
        }
    }
    for (int off = 16; off > 0; off >>= 1)
        contrib += __shfl_down(contrib, off);
    if (lane == 0) out[0] = contrib / 8388608.0f;
}

extern "C" void kernel_launch(void* const* d_in, const int* in_sizes, int n_in,
                              void* d_out, int out_size, void* d_ws, size_t ws_size,
                              hipStream_t stream)
{
    const float* pred   = (const float*)d_in[0];
    const int*   target = (const int*)d_in[1];
    float* out  = (float*)d_out;
    float* buf0 = (float*)d_ws;
    float* buf1 = buf0 + NTOT;
    float* red  = buf1 + NTOT;

    // all reduction slots zero-init (min stored as complement)
    hipMemsetAsync((void*)red, 0, 960 * sizeof(float), stream);

    dim3 grid(64, 32);   // 64 chunks of 8 rows x 32 planes
    stencil_k<true><<<grid, 256, 0, stream>>>(nullptr, buf0, pred, target, red, 0, 1);
    const float* a = buf0;
    float*       b = buf1;
    for (int k = 1; k < 10; k++) {
        stencil_k<false><<<grid, 256, 0, stream>>>(a, b, pred, target, red, k, (k < 9) ? 1 : 0);
        const float* t = a; a = b; b = (float*)t;
    }
    final_out<<<1, 64, 0, stream>>>(red, out);
}

// Round 4
// 273.549 us; speedup vs baseline: 4.4182x; 3.6068x over previous
//
#include <hip/hip_runtime.h>

// Problem constants: B=8, C=4, H=W=512, K_ITERS=10, ALPHA=2
#define Wd   512
#define W4   128               // float4s per row
#define HWp  262144            // elements per (b,c) plane
#define NTOT 8388608           // B*C*H*W

#define F_INF __int_as_float(0x7F800000)

// red[] layout (960 floats, ALL zero-init; per-iteration slots):
//   cmn[k][plane] = red[k*32 + plane]        unsigned ~bits(min)
//                                            (nonneg floats: ~bits is
//                                             monotone-decreasing; init 0
//                                             never wins atomicMax)
//   mx [k][plane] = red[320 + k*32 + plane]  float bits, signed atomicMax
//   sm [k][plane] = red[640 + k*32 + plane]  float atomicAdd

__device__ __forceinline__ float4 bound4(const float* __restrict__ pred,
                                         const int* __restrict__ target,
                                         int plane, int v)
{
    const int b = plane >> 2, c = plane & 3;
    float4 p = ((const float4*)(pred + (size_t)plane * HWp))[v];
    int4   t = ((const int4*)(target + (size_t)b * HWp))[v];
    float dx = p.x - (t.x == c ? 1.0f : 0.0f);
    float dy = p.y - (t.y == c ? 1.0f : 0.0f);
    float dz = p.z - (t.z == c ? 1.0f : 0.0f);
    float dw = p.w - (t.w == c ? 1.0f : 0.0f);
    return make_float4(dx*dx, dy*dy, dz*dz, dw*dw);
}

__device__ __forceinline__ float bound1(const float* __restrict__ pred,
                                        const int* __restrict__ target,
                                        int plane, int i)
{
    const int b = plane >> 2, c = plane & 3;
    float p = pred[(size_t)plane * HWp + i];
    int   t = target[(size_t)b * HWp + i];
    float d = p - (t == c ? 1.0f : 0.0f);
    return d * d;
}

// Round-0-verified per-pass structure: grid (32 chunks x 32 planes), 256
// threads; each thread does 8 row-steps (rows chunk*16 + p*2 + rsub),
// loading u/c/d float4 fresh each step (redundant loads hit L1 and keep
// many vector-memory requests in flight -> hides L2/L3 latency; the
// round-3 rolling-window variant collapsed VGPRs to 24 and serialized
// the loads -> 4x slower). Only change vs round 0: (s,o) derived
// in-kernel from the k-1 reduction slots (no scalars_kernel between
// passes), per-k slots so no reducer resets.
template <bool FIRST>
__global__ __launch_bounds__(256) void stencil_k(const float* __restrict__ in,
                                                 float* __restrict__ out,
                                                 const float* __restrict__ pred,
                                                 const int* __restrict__ target,
                                                 float* __restrict__ red,
                                                 int k, int store)
{
    const int plane = blockIdx.y;
    const int chunk = blockIdx.x;              // 16 rows per chunk

    float s = 1.0f, o = 0.0f;
    if (!FIRST) {
        float mn = __uint_as_float(~((const unsigned*)red)[(k - 1) * 32 + plane]);
        float mx = red[320 + (k - 1) * 32 + plane];
        float denom = mx - mn;
        if (denom != 0.0f) { s = 1.0f / denom; o = -mn / denom; }
    }

    const float* ip = FIRST ? (const float*)nullptr : in + (size_t)plane * HWp;
    float*       op = out + (size_t)plane * HWp;

    const int col4 = threadIdx.x & 127;        // float4 column 0..127
    const int rsub = threadIdx.x >> 7;         // 0..1

    float lmin = F_INF, lmax = 0.0f, lsum = 0.0f;

    const bool hasL = (col4 > 0);
    const bool hasR = (col4 < W4 - 1);

    #pragma unroll
    for (int p = 0; p < 8; p++) {
        const int row = chunk * 16 + p * 2 + rsub;
        const int v   = row * W4 + col4;       // plane-local float4 index
        const bool hasU = (row > 0);
        const bool hasD = (row < Wd - 1);

        float4 c4, u4, d4;
        float lft = 0.0f, rgt = 0.0f;
        if (FIRST) {
            c4 = bound4(pred, target, plane, v);
            u4 = hasU ? bound4(pred, target, plane, v - W4) : make_float4(0,0,0,0);
            d4 = hasD ? bound4(pred, target, plane, v + W4) : make_float4(0,0,0,0);
            if (hasL) lft = bound1(pred, target, plane, 4*v - 1);
            if (hasR) rgt = bound1(pred, target, plane, 4*v + 4);
        } else {
            c4 = ((const float4*)ip)[v];
            u4 = hasU ? ((const float4*)ip)[v - W4] : make_float4(0,0,0,0);
            d4 = hasD ? ((const float4*)ip)[v + W4] : make_float4(0,0,0,0);
            if (hasL) lft = ip[4*v - 1];
            if (hasR) rgt = ip[4*v + 4];
        }

        const float vc = (hasU ? 1.0f : 0.0f) + (hasD ? 1.0f : 0.0f);
        float4 sum, cnt;
        sum.x = c4.x + c4.y + u4.x + d4.x + lft;
        cnt.x = 2.0f + (hasL ? 1.0f : 0.0f) + vc;
        sum.y = c4.x + c4.y + c4.z + u4.y + d4.y;
        cnt.y = 3.0f + vc;
        sum.z = c4.y + c4.z + c4.w + u4.z + d4.z;
        cnt.z = 3.0f + vc;
        sum.w = c4.z + c4.w + rgt + u4.w + d4.w;
        cnt.w = 2.0f + (hasR ? 1.0f : 0.0f) + vc;

        float4 e;
        e.x = fmaxf(0.2f * (s * sum.x + o * cnt.x) - 0.5f, 0.0f);
        e.y = fmaxf(0.2f * (s * sum.y + o * cnt.y) - 0.5f, 0.0f);
        e.z = fmaxf(0.2f * (s * sum.z + o * cnt.z) - 0.5f, 0.0f);
        e.w = fmaxf(0.2f * (s * sum.w + o * cnt.w) - 0.5f, 0.0f);

        if (store) ((float4*)op)[v] = e;

        lmin = fminf(lmin, fminf(fminf(e.x, e.y), fminf(e.z, e.w)));
        lmax = fmaxf(lmax, fmaxf(fmaxf(e.x, e.y), fmaxf(e.z, e.w)));
        lsum += (e.x + e.y) + (e.z + e.w);
    }

    // wave (64-lane) reduction
    for (int off = 32; off > 0; off >>= 1) {
        lmin = fminf(lmin, __shfl_down(lmin, off));
        lmax = fmaxf(lmax, __shfl_down(lmax, off));
        lsum += __shfl_down(lsum, off);
    }
    __shared__ float smin[4], smax[4], ssum[4];
    const int wave = threadIdx.x >> 6;
    if ((threadIdx.x & 63) == 0) { smin[wave] = lmin; smax[wave] = lmax; ssum[wave] = lsum; }
    __syncthreads();
    if (threadIdx.x == 0) {
        float bmin = smin[0], bmax = smax[0], bsum = ssum[0];
        for (int i = 1; i < 4; i++) {
            bmin = fminf(bmin, smin[i]);
            bmax = fmaxf(bmax, smax[i]);
            bsum += ssum[i];
        }
        atomicMax((unsigned*)&red[k * 32 + plane], ~__float_as_uint(bmin));
        atomicMax((int*)&red[320 + k * 32 + plane], __float_as_int(bmax));
        atomicAdd(&red[640 + k * 32 + plane], bsum);
    }
}

// One block, 64 threads: fold all 10x32 plane reductions into the scalar.
__global__ void final_out(const float* __restrict__ red, float* __restrict__ out)
{
    const int lane = threadIdx.x;
    float contrib = 0.0f;
    if (lane < 32) {
        #pragma unroll
        for (int kk = 0; kk < 10; kk++) {
            float mn = __uint_as_float(~((const unsigned*)red)[kk * 32 + lane]);
            float mx = red[320 + kk * 32 + lane];
            float sm = red[640 + kk * 32 + lane];
            float denom = mx - mn;
            float ss = 1.0f, oo = 0.0f;
            if (denom != 0.0f) { ss = 1.0f / denom; oo = -mn / denom; }
            float w = (float)((kk + 1) * (kk + 1));
            contrib += (ss * sm + oo * 262144.0f) * w;
        }
    }
    for (int off = 16; off > 0; off >>= 1)
        contrib += __shfl_down(contrib, off);
    if (lane == 0) out[0] = contrib / 8388608.0f;
}

extern "C" void kernel_launch(void* const* d_in, const int* in_sizes, int n_in,
                              void* d_out, int out_size, void* d_ws, size_t ws_size,
                              hipStream_t stream)
{
    const float* pred   = (const float*)d_in[0];
    const int*   target = (const int*)d_in[1];
    float* out  = (float*)d_out;
    float* buf0 = (float*)d_ws;
    float* buf1 = buf0 + NTOT;
    float* red  = buf1 + NTOT;

    // all reduction slots zero-init (min stored as complement)
    hipMemsetAsync((void*)red, 0, 960 * sizeof(float), stream);

    dim3 grid(32, 32);   // 32 chunks of 16 rows x 32 planes
    stencil_k<true><<<grid, 256, 0, stream>>>(nullptr, buf0, pred, target, red, 0, 1);
    const float* a = buf0;
    float*       b = buf1;
    for (int k = 1; k < 10; k++) {
        stencil_k<false><<<grid, 256, 0, stream>>>(a, b, pred, target, red, k, (k < 9) ? 1 : 0);
        const float* t = a; a = b; b = (float*)t;
    }
    final_out<<<1, 64, 0, stream>>>(red, out);
}